// Round 13
// baseline (312.544 us; speedup 1.0000x reference)
//
#include <hip/hip_runtime.h>

#define NN 8192
#define FI 256
#define FO 128
#define GAT_ALPHA 0.2f

typedef _Float16 f16x8 __attribute__((ext_vector_type(8)));
typedef _Float16 f16x2 __attribute__((ext_vector_type(2)));
typedef float f32x4 __attribute__((ext_vector_type(4)));
typedef unsigned char uchar;
typedef unsigned int uint32;

// ---------------------------------------------------------------------------
// K1: Wh = h@W^T + b (fp32, LDS-tiled)  + fused score/table tail
//   + emits Wfrag (UNSCALED Wh, MFMA-B-fragment-major) via LDS transpose
//   + block 0 zeroes corr and the split-K counters.
//  r4[j]=(s1,e^s1,e^.2s1,0)  c4[j]=(s2,e^s2,e^.2s2,0)  r2[j]=(e^s1,e^.2s1)
// ---------------------------------------------------------------------------
__global__ __launch_bounds__(256) void k1_wh(const float* __restrict__ h,
                                             const float* __restrict__ W,
                                             const float* __restrict__ bias,
                                             const float* __restrict__ a,
                                             float* __restrict__ Wh,
                                             float4* __restrict__ r4,
                                             float4* __restrict__ c4,
                                             float2* __restrict__ r2,
                                             float* __restrict__ s2x,
                                             float* __restrict__ corr,
                                             uint32* __restrict__ counters,
                                             _Float16* __restrict__ Wfrag) {
  __shared__ float hs[32][FI + 1];
  __shared__ __align__(16) float wt[32][FO];
  _Float16* const tileb = (_Float16*)&wt[0][0];  // reused after k-loop: [128 f][64 B rows]
  const int t = threadIdx.x;
  const int j0 = blockIdx.x * 32;
  if (blockIdx.x == 0) {
    if (t < FO) corr[t] = 0.f;
    counters[t] = 0u;
  }
  {
    const int row = t >> 3, c0 = (t & 7) * 32;
    const float* src = h + (size_t)(j0 + row) * FI + c0;
#pragma unroll
    for (int e = 0; e < 8; ++e) {
      float4 v = *(const float4*)(src + 4 * e);
      hs[row][c0 + 4 * e + 0] = v.x;
      hs[row][c0 + 4 * e + 1] = v.y;
      hs[row][c0 + 4 * e + 2] = v.z;
      hs[row][c0 + 4 * e + 3] = v.w;
    }
  }
  const int f4 = (t & 31) * 4;
  const int r0 = (t >> 5) * 4;
  float acc[4][4];
#pragma unroll
  for (int r = 0; r < 4; ++r)
#pragma unroll
    for (int e = 0; e < 4; ++e) acc[r][e] = 0.f;

  for (int kc = 0; kc < FI; kc += 32) {
    __syncthreads();
    {
      const int f = t >> 1, kb = (t & 1) * 16;
      const float* wsrc = W + (size_t)f * FI + kc + kb;
#pragma unroll
      for (int e = 0; e < 16; ++e) wt[kb + e][f] = wsrc[e];
    }
    __syncthreads();
#pragma unroll
    for (int k = 0; k < 32; ++k) {
      const float4 wv = *(const float4*)&wt[k][f4];
      float hv[4];
#pragma unroll
      for (int r = 0; r < 4; ++r) hv[r] = hs[r0 + r][kc + k];
#pragma unroll
      for (int r = 0; r < 4; ++r) {
        acc[r][0] += hv[r] * wv.x;
        acc[r][1] += hv[r] * wv.y;
        acc[r][2] += hv[r] * wv.z;
        acc[r][3] += hv[r] * wv.w;
      }
    }
  }
  __syncthreads();  // wt dead; tileb live from here
  const float4 bv = *(const float4*)&bias[f4];
  const float4 a1v = *(const float4*)&a[f4];
  const float4 a2v = *(const float4*)&a[FO + f4];
  float s1p[4], s2p[4];
#pragma unroll
  for (int r = 0; r < 4; ++r) {
    float4 o;
    o.x = acc[r][0] + bv.x;
    o.y = acc[r][1] + bv.y;
    o.z = acc[r][2] + bv.z;
    o.w = acc[r][3] + bv.w;
    *(float4*)&Wh[(size_t)(j0 + r0 + r) * FO + f4] = o;
    const int jloc = r0 + r;
    const float ov[4] = {o.x, o.y, o.z, o.w};
#pragma unroll
    for (int e = 0; e < 4; ++e) {
      const int gf = f4 + e;  // gf&3 == e
      *(_Float16*)((char*)tileb + gf * 64 + (((unsigned)(jloc * 2)) ^ ((unsigned)(e << 4)))) =
          (_Float16)ov[e];
    }
    s1p[r] = o.x * a1v.x + o.y * a1v.y + o.z * a1v.z + o.w * a1v.w;
    s2p[r] = o.x * a2v.x + o.y * a2v.y + o.z * a2v.z + o.w * a2v.w;
  }
#pragma unroll
  for (int m = 16; m >= 1; m >>= 1) {
#pragma unroll
    for (int r = 0; r < 4; ++r) {
      s1p[r] += __shfl_xor(s1p[r], m);
      s2p[r] += __shfl_xor(s2p[r], m);
    }
  }
  if ((t & 31) == 0) {
#pragma unroll
    for (int r = 0; r < 4; ++r) {
      const int j = j0 + r0 + r;
      const float s1 = s1p[r], s2 = s2p[r];
      const float e1 = expf(s1), e1a = expf(GAT_ALPHA * s1);
      const float e2 = expf(s2), e2a = expf(GAT_ALPHA * s2);
      float4 rv; rv.x = s1; rv.y = e1; rv.z = e1a; rv.w = 0.f;
      float4 cv; cv.x = s2; cv.y = e2; cv.z = e2a; cv.w = 0.f;
      r4[j] = rv;
      c4[j] = cv;
      r2[j] = make_float2(e1, e1a);
      s2x[j] = s2;
    }
  }
  __syncthreads();
  // emit 512 granules (2/thread): granule (kchunk*8+fb)*64+gl holds 8 f16:
  // f = fb*16+(gl&15), j = kchunk*32+(gl>>4)*8+e   (kchunk = blockIdx.x)
#pragma unroll
  for (int q = 0; q < 2; ++q) {
    const int G = t + 256 * q;
    const int fb = G >> 6, gl = G & 63;
    const int gf = fb * 16 + (gl & 15);
    const int jloc = (gl >> 4) * 8;
    const f16x8 v = *(const f16x8*)((const char*)tileb + gf * 64 +
                                    (((unsigned)(jloc * 2)) ^ ((unsigned)((gf & 3) << 4))));
    ((f16x8*)Wfrag)[(size_t)(blockIdx.x * 8 + fb) * 64 + gl] = v;
  }
}

// ---------------------------------------------------------------------------
// K2: single pass over adj (268 MB HBM floor). Thread owns 8 consecutive j
// (2x int4 = 32 B/lane), packs 8 activity bits into one byte, coalesced
// byte stores; 8 accP/accN register accumulators.
// ---------------------------------------------------------------------------
__global__ __launch_bounds__(256) void k2_stats(const int* __restrict__ adj,
                                                const float4* __restrict__ r4,
                                                const float* __restrict__ s2x,
                                                uchar* __restrict__ bitsB,
                                                float2* __restrict__ zpart) {
  __shared__ float4 rs[64];
  const int t = threadIdx.x;
  const int jc = blockIdx.x & 3;
  const int ic = blockIdx.x >> 2;
  const int i0 = ic * 64;
  const int j0 = jc * 2048 + t * 8;
  if (t < 64) rs[t] = r4[i0 + t];
  const float4 ca = *(const float4*)(s2x + j0);
  const float4 cb = *(const float4*)(s2x + j0 + 4);
  const float cx[8] = {ca.x, ca.y, ca.z, ca.w, cb.x, cb.y, cb.z, cb.w};
  float accP[8], accN[8];
#pragma unroll
  for (int e = 0; e < 8; ++e) { accP[e] = 0.f; accN[e] = 0.f; }
  __syncthreads();
  const int4* ap = (const int4*)(adj + (size_t)i0 * NN + j0);
  uchar* bp = bitsB + (size_t)i0 * (NN / 8) + jc * 256 + t;
  for (int ir = 0; ir < 64; ir += 8) {
    int4 av[8][2];
#pragma unroll
    for (int u = 0; u < 8; ++u) {
      av[u][0] = ap[(size_t)(ir + u) * (NN / 4)];
      av[u][1] = ap[(size_t)(ir + u) * (NN / 4) + 1];
    }
#pragma unroll
    for (int u = 0; u < 8; ++u) {
      const float4 ri = rs[ir + u];
      const int aa[8] = {av[u][0].x, av[u][0].y, av[u][0].z, av[u][0].w,
                         av[u][1].x, av[u][1].y, av[u][1].z, av[u][1].w};
      uint32 byte = 0;
#pragma unroll
      for (int e = 0; e < 8; ++e) {
        const bool act = aa[e] > 0;
        byte |= act ? (1u << e) : 0u;
        const bool pos = (ri.x + cx[e]) >= 0.f;
        accP[e] += (act && pos) ? ri.y : 0.f;
        accN[e] += (act && !pos) ? ri.z : 0.f;
      }
      bp[(size_t)(ir + u) * (NN / 8)] = (uchar)byte;
    }
  }
  float2* zp = zpart + (size_t)ic * NN + j0;
#pragma unroll
  for (int e = 0; e < 8; ++e) zp[e] = make_float2(accP[e], accN[e]);
}

// ---------------------------------------------------------------------------
// K3': tiny. Z_j from 128 zpart chunks; write PRE-SCALED f16 tables
//   ey16[j] = e^{s2_j}/Z_j, ez16[j] = e^{.2 s2_j}/Z_j  (0 if empty col).
// Empty cols -> corr[f] += Wh[j][f]/N (uniform-softmax fix; rare).
// ---------------------------------------------------------------------------
__global__ __launch_bounds__(256) void k3_rz(const float4* __restrict__ c4,
                                             const float2* __restrict__ zpart,
                                             const float* __restrict__ Wh,
                                             _Float16* __restrict__ ey16,
                                             _Float16* __restrict__ ez16,
                                             float* __restrict__ corr) {
  const int j = blockIdx.x * 256 + threadIdx.x;
  float p = 0.f, n = 0.f;
#pragma unroll 8
  for (int ic = 0; ic < 128; ++ic) {
    const float2 z = zpart[(size_t)ic * NN + j];
    p += z.x;
    n += z.y;
  }
  const float4 cj = c4[j];
  const float Z = cj.y * p + cj.z * n;
  const float rz = (Z > 0.f) ? 1.f / Z : 0.f;
  ey16[j] = (_Float16)(cj.y * rz);
  ez16[j] = (_Float16)(cj.z * rz);
  if (!(Z > 0.f)) {
    const float* wr = Wh + (size_t)j * FO;
    for (int f = 0; f < FO; ++f) atomicAdd(&corr[f], wr[f] * (1.f / 8192.f));
  }
}

// ---------------------------------------------------------------------------
// K4: partial h' = P @ Wh over this block's K-range; split-K fixup epilogue
// (last block per rowtile sums 4 partials + corr, ELU, writes out -> no k5).
//   P pair = pk_max(pk_mul(rx2, ey'), pk_mul(ry2, ez')) & maskLUT[bitbyte]
//   (ey'/ez' pre-scaled by 1/Z -> inner loop identical to round 11)
// BM=32, 256 thr = 4 waves (1x4), ksplit=4 (2048 cols, 32 steps of 64).
// Grid 1024. B-frags register double-buffered distance-2; barriers drain
// lgkmcnt only; setprio on MFMA.
// ---------------------------------------------------------------------------
#define BARRIER_LDS()                                          \
  do {                                                         \
    __builtin_amdgcn_sched_barrier(0);                         \
    asm volatile("s_waitcnt lgkmcnt(0)" ::: "memory");         \
    __builtin_amdgcn_s_barrier();                              \
    __builtin_amdgcn_sched_barrier(0);                         \
  } while (0)

__global__ __launch_bounds__(256) void k4_main(const uchar* __restrict__ bitsB,
                                               const float2* __restrict__ r2,
                                               const _Float16* __restrict__ ey16,
                                               const _Float16* __restrict__ ez16,
                                               const _Float16* __restrict__ Wfrag,
                                               float* __restrict__ part,
                                               const float* __restrict__ corr,
                                               uint32* __restrict__ counters,
                                               float* __restrict__ out) {
  __shared__ __align__(16) _Float16 P[2][32 * 64];  // 8 KB
  __shared__ uint32 lut[256][4];                    // 4 KB
  __shared__ uint32 lastflag;
  const int t = threadIdx.x;
  const int rowtile = blockIdx.x >> 2;
  const int kq = blockIdx.x & 3;
  const int rowbase = rowtile * 32;
  const int koff = kq * 2048;

  {
#pragma unroll
    for (int p = 0; p < 4; ++p) {
      const uint32 lo = ((t >> (2 * p)) & 1) ? 0x0000FFFFu : 0u;
      const uint32 hi = ((t >> (2 * p + 1)) & 1) ? 0xFFFF0000u : 0u;
      lut[t][p] = lo | hi;
    }
  }

  const int pr = t >> 3, jq = t & 7;
  const float2 rr = r2[rowbase + pr];
  const f16x2 rx2 = {(_Float16)rr.x, (_Float16)rr.x};
  const f16x2 ry2 = {(_Float16)rr.y, (_Float16)rr.y};
  const uchar* bp = bitsB + (size_t)(rowbase + pr) * (NN / 8) + (koff >> 3) + jq;
  const _Float16* eyp = ey16 + koff + jq * 8;
  const _Float16* ezp = ez16 + koff + jq * 8;
  char* const pdst0 = (char*)&P[0][0] + pr * 128 + (((unsigned)(jq * 16)) ^ ((unsigned)((pr & 7) << 4)));
  char* const pdst1 = (char*)&P[1][0] + pr * 128 + (((unsigned)(jq * 16)) ^ ((unsigned)((pr & 7) << 4)));

  const int lane = t & 63, wc = t >> 6;
  const int kgrp = lane >> 4, l15 = lane & 15;
  const unsigned asw = (unsigned)((l15 & 7) << 4);
  const int ar0 = l15 * 128;
  const int ar1 = ar0 + 16 * 128;

  f32x4 acc00 = {0.f, 0.f, 0.f, 0.f}, acc01 = {0.f, 0.f, 0.f, 0.f};
  f32x4 acc10 = {0.f, 0.f, 0.f, 0.f}, acc11 = {0.f, 0.f, 0.f, 0.f};

  uchar mb0, mb1;
  uint4 ey0, ez0, ey1, ez1;
  f16x8 B000, B001, B010, B011, B100, B101, B110, B111;

#define LOADALL(S, MB, EY, EZ, Bq00, Bq01, Bq10, Bq11)                              \
  do {                                                                              \
    MB = bp[(S) * 8];                                                               \
    EY = *(const uint4*)(eyp + (S) * 64);                                           \
    EZ = *(const uint4*)(ezp + (S) * 64);                                           \
    const _Float16* _b = Wfrag + ((size_t)((kq * 64 + (S) * 2) * 8 + wc * 2) * 64 + lane) * 8; \
    Bq00 = *(const f16x8*)(_b);                                                     \
    Bq01 = *(const f16x8*)(_b + 512);                                               \
    Bq10 = *(const f16x8*)(_b + 4096);                                              \
    Bq11 = *(const f16x8*)(_b + 4096 + 512);                                        \
  } while (0)

#define PGEN(DST, MB, EY, EZ)                                                        \
  do {                                                                               \
    const uint4 _m = *(const uint4*)(&lut[MB][0]);                                   \
    const uint32 _eys[4] = {EY.x, EY.y, EY.z, EY.w};                                 \
    const uint32 _ezs[4] = {EZ.x, EZ.y, EZ.z, EZ.w};                                 \
    const uint32 _ms[4] = {_m.x, _m.y, _m.z, _m.w};                                  \
    uint32 _o[4];                                                                    \
    _Pragma("unroll") for (int _p = 0; _p < 4; ++_p) {                               \
      const f16x2 _a = __builtin_bit_cast(f16x2, _eys[_p]) * rx2;                    \
      const f16x2 _b2 = __builtin_bit_cast(f16x2, _ezs[_p]) * ry2;                   \
      const f16x2 _mx = __builtin_elementwise_max(_a, _b2);                          \
      _o[_p] = __builtin_bit_cast(uint32, _mx) & _ms[_p];                            \
    }                                                                                \
    uint4 _st; _st.x = _o[0]; _st.y = _o[1]; _st.z = _o[2]; _st.w = _o[3];           \
    *(uint4*)(DST) = _st;                                                            \
  } while (0)

#define DO_MFMA(BUF, Bq00, Bq01, Bq10, Bq11)                                        \
  do {                                                                              \
    const char* _Pb = (const char*)&P[BUF][0];                                      \
    const f16x8 a00 = *(const f16x8*)(_Pb + ar0 + ((((unsigned)(kgrp * 16))) ^ asw));        \
    const f16x8 a01 = *(const f16x8*)(_Pb + ar0 + (((unsigned)(64 + kgrp * 16)) ^ asw));     \
    const f16x8 a10 = *(const f16x8*)(_Pb + ar1 + ((((unsigned)(kgrp * 16))) ^ asw));        \
    const f16x8 a11 = *(const f16x8*)(_Pb + ar1 + (((unsigned)(64 + kgrp * 16)) ^ asw));     \
    __builtin_amdgcn_s_setprio(1);                                                  \
    acc00 = __builtin_amdgcn_mfma_f32_16x16x32_f16(a00, Bq00, acc00, 0, 0, 0);      \
    acc01 = __builtin_amdgcn_mfma_f32_16x16x32_f16(a00, Bq01, acc01, 0, 0, 0);      \
    acc10 = __builtin_amdgcn_mfma_f32_16x16x32_f16(a10, Bq00, acc10, 0, 0, 0);      \
    acc11 = __builtin_amdgcn_mfma_f32_16x16x32_f16(a10, Bq01, acc11, 0, 0, 0);      \
    acc00 = __builtin_amdgcn_mfma_f32_16x16x32_f16(a01, Bq10, acc00, 0, 0, 0);      \
    acc01 = __builtin_amdgcn_mfma_f32_16x16x32_f16(a01, Bq11, acc01, 0, 0, 0);      \
    acc10 = __builtin_amdgcn_mfma_f32_16x16x32_f16(a11, Bq10, acc10, 0, 0, 0);      \
    acc11 = __builtin_amdgcn_mfma_f32_16x16x32_f16(a11, Bq11, acc11, 0, 0, 0);      \
    __builtin_amdgcn_s_setprio(0);                                                  \
  } while (0)

  // ---- prologue (sync covers lut writes before first PGEN lut read)
  LOADALL(0, mb0, ey0, ez0, B000, B001, B010, B011);
  LOADALL(1, mb1, ey1, ez1, B100, B101, B110, B111);
  __syncthreads();
  PGEN(pdst0, mb0, ey0, ez0);
  BARRIER_LDS();

  for (int s = 0; s < 32; s += 2) {
    PGEN(pdst1, mb1, ey1, ez1);                       // P for step s+1
    DO_MFMA(0, B000, B001, B010, B011);               // step s
    if (s + 2 < 32) LOADALL(s + 2, mb0, ey0, ez0, B000, B001, B010, B011);
    BARRIER_LDS();
    DO_MFMA(1, B100, B101, B110, B111);               // step s+1
    if (s + 2 < 32) PGEN(pdst0, mb0, ey0, ez0);       // P for step s+2
    if (s + 3 < 32) LOADALL(s + 3, mb1, ey1, ez1, B100, B101, B110, B111);
    BARRIER_LDS();
  }

#undef LOADALL
#undef PGEN
#undef DO_MFMA

  // ---- epilogue 1: store this block's partial
  const int orow = rowbase + kgrp * 4;
  const int ocol = wc * 32 + l15;
  float* aP = part + (size_t)kq * NN * FO + (size_t)orow * FO + ocol;
#pragma unroll
  for (int r = 0; r < 4; ++r) {
    aP[(size_t)r * FO] = acc00[r];
    aP[(size_t)r * FO + 16] = acc01[r];
    aP[(size_t)(16 + r) * FO] = acc10[r];
    aP[(size_t)(16 + r) * FO + 16] = acc11[r];
  }

  // ---- epilogue 2: split-K fixup by the last-arriving block of this rowtile
  __threadfence();
  if (t == 0) lastflag = (atomicAdd(&counters[rowtile], 1u) == 3u) ? 1u : 0u;
  __syncthreads();
  if (lastflag) {
    __threadfence();
    const float c0 = corr[ocol];
    const float c1 = corr[ocol + 16];
#pragma unroll
    for (int r = 0; r < 4; ++r) {
      float v00 = c0, v01 = c1, v10 = c0, v11 = c1;
#pragma unroll
      for (int q = 0; q < 4; ++q) {  // fixed order -> deterministic sums
        const float* pp = part + (size_t)q * NN * FO;
        v00 += pp[(size_t)(orow + r) * FO + ocol];
        v01 += pp[(size_t)(orow + r) * FO + ocol + 16];
        v10 += pp[(size_t)(orow + 16 + r) * FO + ocol];
        v11 += pp[(size_t)(orow + 16 + r) * FO + ocol + 16];
      }
      v00 = (v00 > 0.f) ? v00 : (expf(v00) - 1.f);
      v01 = (v01 > 0.f) ? v01 : (expf(v01) - 1.f);
      v10 = (v10 > 0.f) ? v10 : (expf(v10) - 1.f);
      v11 = (v11 > 0.f) ? v11 : (expf(v11) - 1.f);
      out[(size_t)(orow + r) * FO + ocol] = v00;
      out[(size_t)(orow + r) * FO + ocol + 16] = v01;
      out[(size_t)(orow + 16 + r) * FO + ocol] = v10;
      out[(size_t)(orow + 16 + r) * FO + ocol + 16] = v11;
    }
  }
}

// ---------------------------------------------------------------------------
extern "C" void kernel_launch(void* const* d_in, const int* in_sizes, int n_in,
                              void* d_out, int out_size, void* d_ws, size_t ws_size,
                              hipStream_t stream) {
  const float* h = (const float*)d_in[0];
  const int* adj = (const int*)d_in[1];
  const float* W = (const float*)d_in[2];
  const float* b = (const float*)d_in[3];
  const float* a = (const float*)d_in[4];
  float* out = (float*)d_out;
  char* ws = (char*)d_ws;

  // workspace carve (~40 MB total; d_ws ~1 GB per harness poison-fill size)
  float* Wh = (float*)(ws + 0);                                   // 4 MB  [k1..k3']
  _Float16* Wfrag = (_Float16*)(ws + 0x400000);                   // 2 MB  [k1..k4]
  uchar* bits = (uchar*)(ws + 0x600000);                          // 8 MB  [k2..k4]
  float2* zpart = (float2*)(ws + 0xE00000);                       // 8 MB  [k2..k3']
  float4* r4 = (float4*)(ws + 0x1600000);                         // 128 KB
  float4* c4 = (float4*)(ws + 0x1620000);                         // 128 KB
  float2* r2 = (float2*)(ws + 0x1640000);                         // 64 KB
  _Float16* ey16 = (_Float16*)(ws + 0x1650000);                   // 16 KB
  _Float16* ez16 = (_Float16*)(ws + 0x1654000);                   // 16 KB
  float* s2x = (float*)(ws + 0x1658000);                          // 32 KB
  float* corr = (float*)(ws + 0x1660000);                         // 512 B
  uint32* counters = (uint32*)(ws + 0x1661000);                   // 1 KB
  float* part = (float*)(ws + 0x1700000);                         // 16 MB [k4]

  k1_wh<<<NN / 32, 256, 0, stream>>>(h, W, b, a, Wh, r4, c4, r2, s2x, corr, counters, Wfrag);
  k2_stats<<<512, 256, 0, stream>>>(adj, r4, s2x, bits, zpart);
  k3_rz<<<32, 256, 0, stream>>>(c4, zpart, Wh, ey16, ez16, corr);
  k4_main<<<1024, 256, 0, stream>>>(bits, r2, ey16, ez16, Wfrag, part, corr, counters, out);
}